// Round 1
// 159.242 us; speedup vs baseline: 1.0213x; 1.0213x over previous
//
#include <hip/hip_runtime.h>
#include <math.h>

#define N_     256
#define C_     2048
#define HW_    49
#define CHUNKS 4
#define CPB    (C_/CHUNKS)     // 512 channels per block
#define TILE_C 64
#define NTILE  (CPB/TILE_C)    // 8 tiles per block
#define NG     5               // groups: sum, u0, u1, t0, t1
#define TILE_BYTES (TILE_C*HW_*4)   // 12544 = 12*1024 + 256

// ---------------------------------------------------------------------------
// async 16B global->LDS copy (wave-uniform LDS base + lane*16, per-lane gaddr)
// ---------------------------------------------------------------------------
__device__ __forceinline__ void cp16(const void* gptr, unsigned lds_off) {
  __builtin_amdgcn_global_load_lds(
      (const __attribute__((address_space(1))) unsigned int*)gptr,
      (__attribute__((address_space(3))) unsigned int*)lds_off,
      16, 0, 0);
}

// stage one 64ch x 49pos tile (12544 B): each of 4 waves issues exactly 4 ops
// (3 full 1KiB segments + 64B quarter of the 256B tail) -> uniform vmcnt math
__device__ __forceinline__ void stage_tile(const float* src, unsigned lb,
                                           int wave, int lane) {
  const char* s = (const char*)src;
  #pragma unroll
  for (int i = 0; i < 3; ++i) {
    const int seg = wave + i*4;                 // 0..11
    cp16(s + seg*1024 + lane*16, lb + (unsigned)(seg*1024));
  }
  if (lane < 4)                                 // tail 256B split 4 ways
    cp16(s + 12288 + wave*64 + lane*16, lb + (unsigned)(12288 + wave*64));
}

// ---------------------------------------------------------------------------
// Kernel 1: 5 weighted channel-reductions, double-buffered async staging.
// part[n][chunk][g*49+p] = sum over chunk's channels of x[n,c,p]*w_g[c]
// ---------------------------------------------------------------------------
__global__ __launch_bounds__(256) void k_reduce(const float* __restrict__ x,
                                                const float* __restrict__ Wm,
                                                float* __restrict__ part) {
  const int chunk = blockIdx.x;   // 0..3
  const int n     = blockIdx.y;   // 0..255
  const int t     = threadIdx.x;
  const int wave  = t >> 6;
  const int lane  = t & 63;

  __shared__ __align__(16) float  buf[2][TILE_C*HW_];  // 2 x 12544 B
  __shared__ float4 wt4[CPB];                          // 8 KiB

  const unsigned lb0 = (unsigned)(size_t)&buf[0][0];
  const unsigned lb1 = (unsigned)(size_t)&buf[1][0];

  const float* xbase = x + ((size_t)n*C_ + (size_t)chunk*CPB)*HW_;

  // weights for this block's channels: wt4[c] = (W0u, W1u, W0t, W1t)
  for (int c = t; c < CPB; c += 256) {
    const int gc = chunk*CPB + c;
    float4 w;
    w.x = Wm[0*(2*C_)       + gc];
    w.y = Wm[1*(2*C_)       + gc];
    w.z = Wm[0*(2*C_) + C_  + gc];
    w.w = Wm[1*(2*C_) + C_  + gc];
    wt4[c] = w;
  }

  stage_tile(xbase, lb0, wave, lane);      // tile 0 in flight

  asm volatile("s_waitcnt lgkmcnt(0)" ::: "memory");   // wt4 visible
  __builtin_amdgcn_s_barrier();

  // each active lane (wave 0, p<49) owns one position, all 5 groups
  const int  p   = lane;
  const bool act = (wave == 0) && (lane < HW_);

  float a0 = 0.f, a1 = 0.f, a2 = 0.f, a3 = 0.f, a4 = 0.f;

  for (int tt = 0; tt < NTILE; ++tt) {
    if (tt < NTILE-1) {
      stage_tile(xbase + (size_t)(tt+1)*TILE_C*HW_,
                 (tt & 1) ? lb0 : lb1, wave, lane);
      asm volatile("s_waitcnt vmcnt(4)" ::: "memory");  // tile tt landed,
    } else {                                            // tile tt+1 in flight
      asm volatile("s_waitcnt vmcnt(0)" ::: "memory");
    }
    __builtin_amdgcn_s_barrier();

    if (act) {
      const float*  tl = buf[tt & 1];
      const float4* wp = &wt4[tt*TILE_C];
      #pragma unroll 16
      for (int c = 0; c < TILE_C; ++c) {
        const float  v = tl[c*HW_ + p];   // <=2-way bank alias (free, m136)
        const float4 w = wp[c];           // same addr all lanes: broadcast
        a0 += v;
        a1 = fmaf(v, w.x, a1);
        a2 = fmaf(v, w.y, a2);
        a3 = fmaf(v, w.z, a3);
        a4 = fmaf(v, w.w, a4);
      }
    }
    asm volatile("s_waitcnt lgkmcnt(0)" ::: "memory");  // done reading buf
    __builtin_amdgcn_s_barrier();                       // before its reuse
  }

  if (act) {
    float* dst = part + ((size_t)n*CHUNKS + chunk)*(NG*HW_);
    dst[0*HW_ + p] = a0;
    dst[1*HW_ + p] = a1;
    dst[2*HW_ + p] = a2;
    dst[3*HW_ + p] = a3;
    dst[4*HW_ + p] = a4;
  }
}

// ---------------------------------------------------------------------------
// Kernel 2: per-n epilogue. One block per n.
// ---------------------------------------------------------------------------
__global__ __launch_bounds__(256) void k_final(const float* __restrict__ part,
                                               const float* __restrict__ mask,
                                               const float* __restrict__ b,
                                               float* __restrict__ out) {
  const int n = blockIdx.x;
  const int t = threadIdx.x;
  __shared__ float red[NG*HW_];

  if (t < NG*HW_) {
    float a = 0.f;
    #pragma unroll
    for (int ch = 0; ch < CHUNKS; ++ch)
      a += part[((size_t)n*CHUNKS + ch)*(NG*HW_) + t];
    red[t] = a;
  }
  __syncthreads();

  if (t < 64) {
    const int  p   = t;
    const bool act = (p < HW_);

    // threshold = mean(mask[n]); binary mask strict >
    float m = act ? mask[n*HW_ + p] : 0.f;
    float tot = m;
    #pragma unroll
    for (int off = 32; off; off >>= 1) tot += __shfl_xor(tot, off);
    const float thr = tot / 49.f;

    // masked_mean and first-index argmax over 49 positions
    float s  = act ? red[0*HW_ + p] : 0.f;
    float mm = act ? ((m > thr) ? (s * (1.f/2048.f)) : 0.f) : -INFINITY;
    float best = mm;
    int   bidx = act ? p : 64;
    #pragma unroll
    for (int off = 32; off; off >>= 1) {
      float ov = __shfl_xor(best, off);
      int   oi = __shfl_xor(bidx, off);
      if (ov > best || (ov == best && oi < bidx)) { best = ov; bidx = oi; }
    }
    const int mi = bidx;   // uniform across wave

    const float u0mi = red[1*HW_ + mi];
    const float u1mi = red[2*HW_ + mi];

    float pred0 = 0.f, pred1 = 0.f;
    if (act) {
      pred0 = fmaxf(u0mi + red[3*HW_ + p] + b[0], 0.f);
      pred1 = fmaxf(u1mi + red[4*HW_ + p] + b[1], 0.f);
      if (p == mi) { pred0 = 0.f; pred1 = 0.f; }
    }

    // geometry
    const int ii = p / 7,  jj = p - ii*7;
    const int ai = mi / 7, aj = mi - ai*7;
    const float ri = (float)(ii - ai) / 7.f;
    const float rj = (float)(jj - aj) / 7.f;
    const float dist = sqrtf(ri*ri + rj*rj);
    const float ang  = (atan2f(rj, ri) / 3.14159274101257324f + 1.f) * 0.5f;

    float gap = pred1 - ang;
    if (gap < 0.f) gap += 1.f;
    float gsum = act ? gap : 0.f;
    #pragma unroll
    for (int off = 32; off; off >>= 1) gsum += __shfl_xor(gsum, off);
    const float gmean = gsum / 49.f;

    if (act) {
      const float dl = pred0 - dist;
      const float ga = gap - gmean;
      out[n*HW_ + p] = dl*dl + ga*ga;
    }
  }
}

extern "C" void kernel_launch(void* const* d_in, const int* in_sizes, int n_in,
                              void* d_out, int out_size, void* d_ws, size_t ws_size,
                              hipStream_t stream) {
  const float* x    = (const float*)d_in[0];  // (256, 2048, 7, 7)
  const float* mask = (const float*)d_in[1];  // (256, 7, 7)
  const float* Wm   = (const float*)d_in[2];  // (2, 4096)
  const float* b    = (const float*)d_in[3];  // (2,)
  float* out  = (float*)d_out;                // (256, 7, 7)
  float* part = (float*)d_ws;                 // 256*4*245 floats ~= 1.0 MB

  dim3 g1(CHUNKS, N_);
  k_reduce<<<g1, 256, 0, stream>>>(x, Wm, part);
  k_final<<<N_, 256, 0, stream>>>(part, mask, b, out);
}

// Round 2
// 159.013 us; speedup vs baseline: 1.0228x; 1.0014x over previous
//
#include <hip/hip_runtime.h>
#include <math.h>

#define N_     256
#define C_     2048
#define HW_    49
#define CHUNKS 2
#define CPB    (C_/CHUNKS)     // 1024 channels per block
#define WCH    (CPB/4)         // 256 channels per wave
#define TILE_C 32              // channels per wave-tile
#define NTILE  (WCH/TILE_C)    // 8 tiles per wave
#define NG     5               // groups: sum, u0, u1, t0, t1
#define PARTS  (CHUNKS*4)      // 8 partials per n (chunk x wave)
#define TBYTES (TILE_C*HW_*4)  // 6272 = 6*1024 + 128

// ---------------------------------------------------------------------------
// async 16B global->LDS copy (wave-uniform LDS base + lane*16, per-lane gaddr)
// ---------------------------------------------------------------------------
__device__ __forceinline__ void cp16(const void* gptr, unsigned lds_off) {
  __builtin_amdgcn_global_load_lds(
      (const __attribute__((address_space(1))) unsigned int*)gptr,
      (__attribute__((address_space(3))) unsigned int*)lds_off,
      16, 0, 0);
}

// stage one private 32ch x 49pos tile (6272 B): exactly 7 vmem ops per wave
// (6 full 1KiB segments + one 128B tail with lanes 0..7 active)
__device__ __forceinline__ void stage_tile(const float* src, unsigned lb,
                                           int lane) {
  const char* s = (const char*)src;
  #pragma unroll
  for (int i = 0; i < 6; ++i)
    cp16(s + i*1024 + lane*16, lb + (unsigned)(i*1024));
  if (lane < 8)
    cp16(s + 6144 + lane*16, lb + 6144u);
}

// ---------------------------------------------------------------------------
// Kernel 1: 5 weighted channel-reductions. Wave-private streaming:
// each wave owns 256 channels, double-buffers its own LDS tile, NO barriers
// in the main loop (buf is wave-private; vmcnt/lgkmcnt are per-wave).
// part[n][chunk*4+wave][g*49+p] = sum over wave's channels of x[n,c,p]*w_g[c]
// ---------------------------------------------------------------------------
__global__ __launch_bounds__(256) void k_reduce(const float* __restrict__ x,
                                                const float* __restrict__ Wm,
                                                float* __restrict__ part) {
  const int chunk = blockIdx.x;   // 0..1
  const int n     = blockIdx.y;   // 0..255
  const int t     = threadIdx.x;
  const int wave  = t >> 6;
  const int lane  = t & 63;

  __shared__ __align__(16) float buf[4][2][TILE_C*HW_];  // 4 waves x 2 x 6272B
  __shared__ float4 wt4[CPB];                            // 16 KiB

  // weights for this block's channels: wt4[c] = (W0u, W1u, W0t, W1t)
  #pragma unroll
  for (int c = t; c < CPB; c += 256) {
    const int gc = chunk*CPB + c;
    float4 w;
    w.x = Wm[0*(2*C_)       + gc];   // W[0, c]      -> u0
    w.y = Wm[1*(2*C_)       + gc];   // W[1, c]      -> u1
    w.z = Wm[0*(2*C_) + C_  + gc];   // W[0, C+c]    -> t0
    w.w = Wm[1*(2*C_) + C_  + gc];   // W[1, C+c]    -> t1
    wt4[c] = w;
  }
  __syncthreads();   // wt4 visible; everything drained (clean vmcnt slate)

  const float* wbase = x + ((size_t)n*C_ + (size_t)chunk*CPB
                            + (size_t)wave*WCH)*HW_;
  const unsigned lb0 = (unsigned)(size_t)&buf[wave][0][0];
  const unsigned lb1 = (unsigned)(size_t)&buf[wave][1][0];

  stage_tile(wbase, lb0, lane);          // tile 0 in flight (7 ops)

  const int  p   = lane;
  const bool act = (lane < HW_);

  float a0 = 0.f, a1 = 0.f, a2 = 0.f, a3 = 0.f, a4 = 0.f;

  #pragma unroll 2
  for (int tt = 0; tt < NTILE; ++tt) {
    if (tt < NTILE-1) {
      stage_tile(wbase + (size_t)(tt+1)*TILE_C*HW_,
                 (tt & 1) ? lb0 : lb1, lane);
      asm volatile("s_waitcnt vmcnt(7)" ::: "memory");  // tile tt landed,
    } else {                                            // tile tt+1 in flight
      asm volatile("s_waitcnt vmcnt(0)" ::: "memory");
    }

    if (act) {
      const float*  tl = &buf[wave][tt & 1][0];
      const float4* wp = &wt4[wave*WCH + tt*TILE_C];
      #pragma unroll 8
      for (int c = 0; c < TILE_C; ++c) {
        const float  v = tl[c*HW_ + p];   // <=2-way bank alias (free, m136)
        const float4 w = wp[c];           // same addr all lanes: broadcast
        a0 += v;
        a1 = fmaf(v, w.x, a1);
        a2 = fmaf(v, w.y, a2);
        a3 = fmaf(v, w.z, a3);
        a4 = fmaf(v, w.w, a4);
      }
    }
    // all ds_reads of this buffer complete before it can be overwritten
    asm volatile("s_waitcnt lgkmcnt(0)" ::: "memory");
  }

  if (act) {
    float* dst = part + ((size_t)n*PARTS + (size_t)(chunk*4 + wave))*(NG*HW_);
    dst[0*HW_ + p] = a0;
    dst[1*HW_ + p] = a1;
    dst[2*HW_ + p] = a2;
    dst[3*HW_ + p] = a3;
    dst[4*HW_ + p] = a4;
  }
}

// ---------------------------------------------------------------------------
// Kernel 2: per-n epilogue. One block per n.
// ---------------------------------------------------------------------------
__global__ __launch_bounds__(256) void k_final(const float* __restrict__ part,
                                               const float* __restrict__ mask,
                                               const float* __restrict__ b,
                                               float* __restrict__ out) {
  const int n = blockIdx.x;
  const int t = threadIdx.x;
  __shared__ float red[NG*HW_];

  if (t < NG*HW_) {
    float a = 0.f;
    #pragma unroll
    for (int ch = 0; ch < PARTS; ++ch)
      a += part[((size_t)n*PARTS + ch)*(NG*HW_) + t];
    red[t] = a;
  }
  __syncthreads();

  if (t < 64) {
    const int  p   = t;
    const bool act = (p < HW_);

    // threshold = mean(mask[n]); binary mask strict >
    float m = act ? mask[n*HW_ + p] : 0.f;
    float tot = m;
    #pragma unroll
    for (int off = 32; off; off >>= 1) tot += __shfl_xor(tot, off);
    const float thr = tot / 49.f;

    // masked_mean and first-index argmax over 49 positions
    float s  = act ? red[0*HW_ + p] : 0.f;
    float mm = act ? ((m > thr) ? (s * (1.f/2048.f)) : 0.f) : -INFINITY;
    float best = mm;
    int   bidx = act ? p : 64;
    #pragma unroll
    for (int off = 32; off; off >>= 1) {
      float ov = __shfl_xor(best, off);
      int   oi = __shfl_xor(bidx, off);
      if (ov > best || (ov == best && oi < bidx)) { best = ov; bidx = oi; }
    }
    const int mi = bidx;   // uniform across wave

    const float u0mi = red[1*HW_ + mi];
    const float u1mi = red[2*HW_ + mi];

    float pred0 = 0.f, pred1 = 0.f;
    if (act) {
      pred0 = fmaxf(u0mi + red[3*HW_ + p] + b[0], 0.f);
      pred1 = fmaxf(u1mi + red[4*HW_ + p] + b[1], 0.f);
      if (p == mi) { pred0 = 0.f; pred1 = 0.f; }
    }

    // geometry
    const int ii = p / 7,  jj = p - ii*7;
    const int ai = mi / 7, aj = mi - ai*7;
    const float ri = (float)(ii - ai) / 7.f;
    const float rj = (float)(jj - aj) / 7.f;
    const float dist = sqrtf(ri*ri + rj*rj);
    const float ang  = (atan2f(rj, ri) / 3.14159274101257324f + 1.f) * 0.5f;

    float gap = pred1 - ang;
    if (gap < 0.f) gap += 1.f;
    float gsum = act ? gap : 0.f;
    #pragma unroll
    for (int off = 32; off; off >>= 1) gsum += __shfl_xor(gsum, off);
    const float gmean = gsum / 49.f;

    if (act) {
      const float dl = pred0 - dist;
      const float ga = gap - gmean;
      out[n*HW_ + p] = dl*dl + ga*ga;
    }
  }
}

extern "C" void kernel_launch(void* const* d_in, const int* in_sizes, int n_in,
                              void* d_out, int out_size, void* d_ws, size_t ws_size,
                              hipStream_t stream) {
  const float* x    = (const float*)d_in[0];  // (256, 2048, 7, 7)
  const float* mask = (const float*)d_in[1];  // (256, 7, 7)
  const float* Wm   = (const float*)d_in[2];  // (2, 4096)
  const float* b    = (const float*)d_in[3];  // (2,)
  float* out  = (float*)d_out;                // (256, 7, 7)
  float* part = (float*)d_ws;                 // 256*8*245 floats ~= 1.9 MB

  dim3 g1(CHUNKS, N_);
  k_reduce<<<g1, 256, 0, stream>>>(x, Wm, part);
  k_final<<<N_, 256, 0, stream>>>(part, mask, b, out);
}

// Round 3
// 156.086 us; speedup vs baseline: 1.0420x; 1.0187x over previous
//
#include <hip/hip_runtime.h>
#include <math.h>

#define N_     256
#define C_     2048
#define HW_    49
#define NW     16              // waves per block (1024 threads)
#define WCH    (C_/NW)         // 128 channels per wave
#define TILE_C 16              // channels per wave-tile
#define NTILE  (WCH/TILE_C)    // 8 tiles per wave
#define NG     5               // groups: sum, u0, u1, t0, t1
#define TFLOAT (TILE_C*HW_)    // 784 floats = 3136 B = 3*1024 + 64

// ---------------------------------------------------------------------------
// async 16B global->LDS copy (wave-uniform LDS base + lane*16, per-lane gaddr)
// ---------------------------------------------------------------------------
__device__ __forceinline__ void cp16(const void* gptr, unsigned lds_off) {
  __builtin_amdgcn_global_load_lds(
      (const __attribute__((address_space(1))) unsigned int*)gptr,
      (__attribute__((address_space(3))) unsigned int*)lds_off,
      16, 0, 0);
}

// stage one private 16ch x 49pos tile (3136 B): exactly 4 vmem ops per wave
// (3 full 1KiB segments + one 64B tail with lanes 0..3 active)
__device__ __forceinline__ void stage_tile(const float* src, unsigned lb,
                                           int lane) {
  const char* s = (const char*)src;
  #pragma unroll
  for (int i = 0; i < 3; ++i)
    cp16(s + i*1024 + lane*16, lb + (unsigned)(i*1024));
  if (lane < 4)
    cp16(s + 3072 + lane*16, lb + 3072u);
}

// ---------------------------------------------------------------------------
// Fused kernel: one block per n (16 waves). Each wave streams its private
// 128-channel slice through a wave-private LDS double buffer (no barriers in
// the main loop; counted vmcnt only). Then a block-level reduction of the
// 16x(5x49) partials and the epilogue run in-place — no part buffer, no
// second dispatch.
// ---------------------------------------------------------------------------
__global__ __launch_bounds__(1024) void k_fused(const float* __restrict__ x,
                                                const float* __restrict__ mask,
                                                const float* __restrict__ Wm,
                                                const float* __restrict__ b,
                                                float* __restrict__ out) {
  const int n    = blockIdx.x;
  const int t    = threadIdx.x;
  const int wave = t >> 6;
  const int lane = t & 63;

  __shared__ __align__(16) float buf[NW][2][TFLOAT];  // 100,352 B
  __shared__ float4 wt4[C_];                          //  32,768 B
  __shared__ float  red[NW][NG*HW_];                  //  15,680 B
  __shared__ float  rsum[NG*HW_];                     //     980 B

  // weights: wt4[c] = (W[0,c], W[1,c], W[0,C+c], W[1,C+c])
  #pragma unroll
  for (int c = t; c < C_; c += 1024) {
    float4 w;
    w.x = Wm[c];            // W[0, c]      -> u0
    w.y = Wm[2*C_ + c];     // W[1, c]      -> u1
    w.z = Wm[C_   + c];     // W[0, C+c]    -> t0
    w.w = Wm[3*C_ + c];     // W[1, C+c]    -> t1
    wt4[c] = w;
  }
  __syncthreads();   // wt4 visible; full drain -> clean vmcnt slate

  const float* wbase = x + ((size_t)n*C_ + (size_t)wave*WCH)*HW_;
  const unsigned lb0 = (unsigned)(size_t)&buf[wave][0][0];
  const unsigned lb1 = (unsigned)(size_t)&buf[wave][1][0];

  stage_tile(wbase, lb0, lane);          // tile 0 in flight (4 ops)

  const int  p   = lane;
  const bool act = (lane < HW_);

  float a0 = 0.f, a1 = 0.f, a2 = 0.f, a3 = 0.f, a4 = 0.f;

  #pragma unroll 2
  for (int tt = 0; tt < NTILE; ++tt) {
    if (tt < NTILE-1) {
      stage_tile(wbase + (size_t)(tt+1)*TFLOAT,
                 (tt & 1) ? lb0 : lb1, lane);
      asm volatile("s_waitcnt vmcnt(4)" ::: "memory");  // tile tt landed,
    } else {                                            // tile tt+1 in flight
      asm volatile("s_waitcnt vmcnt(0)" ::: "memory");
    }

    if (act) {
      const float*  tl = &buf[wave][tt & 1][0];
      const float4* wp = &wt4[wave*WCH + tt*TILE_C];
      #pragma unroll
      for (int c = 0; c < TILE_C; ++c) {
        const float  v = tl[c*HW_ + p];   // <=2-way bank alias (free, m136)
        const float4 w = wp[c];           // same addr all lanes: broadcast
        a0 += v;
        a1 = fmaf(v, w.x, a1);
        a2 = fmaf(v, w.y, a2);
        a3 = fmaf(v, w.z, a3);
        a4 = fmaf(v, w.w, a4);
      }
    }
    // all ds_reads of this buffer complete before it can be overwritten
    asm volatile("s_waitcnt lgkmcnt(0)" ::: "memory");
  }

  if (act) {
    red[wave][0*HW_ + p] = a0;
    red[wave][1*HW_ + p] = a1;
    red[wave][2*HW_ + p] = a2;
    red[wave][3*HW_ + p] = a3;
    red[wave][4*HW_ + p] = a4;
  }
  __syncthreads();

  // 16-way cross-wave reduction (threads 0..244)
  if (t < NG*HW_) {
    float s = 0.f;
    #pragma unroll
    for (int w = 0; w < NW; ++w) s += red[w][t];
    rsum[t] = s;
  }
  __syncthreads();

  // ---- epilogue: wave 0 only ----
  if (t < 64) {
    const int  pp  = t;
    const bool ac  = (pp < HW_);

    // threshold = mean(mask[n]); binary mask strict >
    float m = ac ? mask[n*HW_ + pp] : 0.f;
    float tot = m;
    #pragma unroll
    for (int off = 32; off; off >>= 1) tot += __shfl_xor(tot, off);
    const float thr = tot / 49.f;

    // masked_mean and first-index argmax over 49 positions
    float s  = ac ? rsum[0*HW_ + pp] : 0.f;
    float mm = ac ? ((m > thr) ? (s * (1.f/2048.f)) : 0.f) : -INFINITY;
    float best = mm;
    int   bidx = ac ? pp : 64;
    #pragma unroll
    for (int off = 32; off; off >>= 1) {
      float ov = __shfl_xor(best, off);
      int   oi = __shfl_xor(bidx, off);
      if (ov > best || (ov == best && oi < bidx)) { best = ov; bidx = oi; }
    }
    const int mi = bidx;   // uniform across wave

    const float u0mi = rsum[1*HW_ + mi];
    const float u1mi = rsum[2*HW_ + mi];

    float pred0 = 0.f, pred1 = 0.f;
    if (ac) {
      pred0 = fmaxf(u0mi + rsum[3*HW_ + pp] + b[0], 0.f);
      pred1 = fmaxf(u1mi + rsum[4*HW_ + pp] + b[1], 0.f);
      if (pp == mi) { pred0 = 0.f; pred1 = 0.f; }
    }

    // geometry
    const int ii = pp / 7,  jj = pp - ii*7;
    const int ai = mi / 7,  aj = mi - ai*7;
    const float ri = (float)(ii - ai) / 7.f;
    const float rj = (float)(jj - aj) / 7.f;
    const float dist = sqrtf(ri*ri + rj*rj);
    const float ang  = (atan2f(rj, ri) / 3.14159274101257324f + 1.f) * 0.5f;

    float gap = pred1 - ang;
    if (gap < 0.f) gap += 1.f;
    float gsum = ac ? gap : 0.f;
    #pragma unroll
    for (int off = 32; off; off >>= 1) gsum += __shfl_xor(gsum, off);
    const float gmean = gsum / 49.f;

    if (ac) {
      const float dl = pred0 - dist;
      const float ga = gap - gmean;
      out[n*HW_ + pp] = dl*dl + ga*ga;
    }
  }
}

extern "C" void kernel_launch(void* const* d_in, const int* in_sizes, int n_in,
                              void* d_out, int out_size, void* d_ws, size_t ws_size,
                              hipStream_t stream) {
  const float* x    = (const float*)d_in[0];  // (256, 2048, 7, 7)
  const float* mask = (const float*)d_in[1];  // (256, 7, 7)
  const float* Wm   = (const float*)d_in[2];  // (2, 4096)
  const float* b    = (const float*)d_in[3];  // (2,)
  float* out  = (float*)d_out;                // (256, 7, 7)
  (void)d_ws; (void)ws_size;                  // workspace no longer needed

  k_fused<<<dim3(N_), 1024, 0, stream>>>(x, mask, Wm, b, out);
}